// Round 9
// baseline (174.735 us; speedup 1.0000x reference)
//
#include <hip/hip_runtime.h>

// B=4, C=256, H=W=64, O=256, K=3, PAD=2, DIL=2; offset conv: 18ch 3x3 p1 d1.
// R9: (1) channel-octet LDS layout [pos][64ch] (stride 144B): sampling corner
// read = ONE ds_read_b128 (8 ch) instead of 4 scalar b32 -> ~6x less LDS-pipe
// traffic; colf writes/reads XOR-slot-swizzled to be conflict-free.
// (2) offset conv FUSED into deform as an MFMA prologue on the same staged
// windows (no off_buf round-trip / memset / atomics / extra launch); main
// GEMM loop runs cb order {2,3,0,1} to reuse the conv's last staged buffers.
// K order k = cb*576 + n*64 + cl (R7/R8-verified frag layouts unchanged).

typedef __attribute__((ext_vector_type(8))) short short8;
typedef __attribute__((ext_vector_type(4))) float floatx4;

__device__ inline unsigned short f2bf(float f) {  // RNE fp32 -> bf16 bits
  unsigned int u = __float_as_uint(f);
  u += 0x7fff + ((u >> 16) & 1);
  return (unsigned short)(u >> 16);
}
__device__ inline float bflo(unsigned int u) { return __uint_as_float(u << 16); }
__device__ inline float bfhi(unsigned int u) {
  return __uint_as_float(u & 0xffff0000u);
}

// ---------------------------------------------------------------------------
// prep (unchanged, R7/R8-verified).
// wfrag:  [ci=36][mt=16][kt=2][lane=64][j=8], val = dw[o=mt*16+(lane&15)]
//         [c*9+n], c = cb*64+kt*32+(lane>>4)*8+j, cb=ci/9, n=ci%9.
// wfragA: [ci=36][kt=2][mt=2][lane=64][j=8], val = (o<18)?ow[o][c*9+t]:0.
// ---------------------------------------------------------------------------
__global__ __launch_bounds__(256) void prep_kernel(
    const float* __restrict__ dw, const float* __restrict__ ow,
    unsigned short* __restrict__ wfrag, unsigned short* __restrict__ wfragA) {
  int idx = blockIdx.x * 256 + threadIdx.x;
  if (idx < 73728) {
    int ci = idx >> 11;
    int mt = (idx >> 7) & 15;
    int kt = (idx >> 6) & 1;
    int lane = idx & 63;
    int cb = ci / 9, n = ci - cb * 9;
    int o = mt * 16 + (lane & 15);
    int cbase = cb * 64 + kt * 32 + (lane >> 4) * 8;
    short8 v;
#pragma unroll
    for (int j = 0; j < 8; ++j)
      v[j] = (short)f2bf(dw[o * 2304 + (cbase + j) * 9 + n]);
    *((short8*)wfrag + idx) = v;
  } else {
    int e = idx - 73728;
    if (e < 9216) {
      int ci = e >> 8;
      int kt = (e >> 7) & 1;
      int mt = (e >> 6) & 1;
      int lane = e & 63;
      int cb = ci / 9, t = ci - cb * 9;
      int o = mt * 16 + (lane & 15);
      int cbase = cb * 64 + kt * 32 + (lane >> 4) * 8;
      short8 v;
      if (o < 18) {
#pragma unroll
        for (int j = 0; j < 8; ++j)
          v[j] = (short)f2bf(ow[o * 2304 + (cbase + j) * 9 + t]);
      } else {
        v = (short8)0;
      }
      *((short8*)wfragA + e) = v;
    }
  }
}

// ---------------------------------------------------------------------------
// Stage one cb (64 ch) into octet layout: dst[pos*72 + ch] bf16, pos =
// ry*15+rx over the 15x15 halo window (origin h0-3, w0-3), OOB -> 0.
// Thread unit = (oct, pos): 8 coalesced global loads -> 1 ds_write_b128.
// ---------------------------------------------------------------------------
__device__ __forceinline__ void stage_cb8(unsigned short* __restrict__ dst,
                                          const float* __restrict__ xb, int cb,
                                          int h0, int w0, int tid) {
  for (int e = tid; e < 1800; e += 512) {
    int oct = e / 225, pos = e - oct * 225;
    int ry = pos / 15, rx = pos - ry * 15;
    int gy = h0 - 3 + ry, gx = w0 - 3 + rx;
    bool ok = (gy >= 0 && gy < 64 && gx >= 0 && gx < 64);
    const float* p0 =
        xb + ((size_t)(cb * 64 + oct * 8)) * 4096 + (ok ? gy * 64 + gx : 0);
    unsigned int s[8];
#pragma unroll
    for (int j = 0; j < 8; ++j)
      s[j] = ok ? (unsigned int)f2bf(p0[(size_t)j * 4096]) : 0u;
    uint4 v;
    v.x = s[0] | (s[1] << 16);
    v.y = s[2] | (s[3] << 16);
    v.z = s[4] | (s[5] << 16);
    v.w = s[6] | (s[7] << 16);
    *(uint4*)&dst[pos * 72 + oct * 8] = v;
  }
}

// ---------------------------------------------------------------------------
// Sampler for one chunk (cb, n): thread = (px = tid>>3, oct = tid&7).
// 4 corner ds_read_b128 (8 ch each) -> bilinear (float2) -> truncate-bf16 ->
// one ds_write_b128 into colf at XOR-swizzled slot. kl == cl = oct*8+j.
// ---------------------------------------------------------------------------
__device__ __forceinline__ void sample_chunk8(
    const unsigned short* __restrict__ sx, int n,
    unsigned short* __restrict__ colf, int px, int oct,
    const float (*sw4)[64][4], const short (*scoff)[64]) {
  float4 wq = *(const float4*)&sw4[n][px][0];
  const unsigned short* p = sx + (int)scoff[n][px] * 72 + oct * 8;
  uint4 c00 = *(const uint4*)(p);
  uint4 c01 = *(const uint4*)(p + 72);
  uint4 c10 = *(const uint4*)(p + 15 * 72);
  uint4 c11 = *(const uint4*)(p + 16 * 72);
  const unsigned int* u00 = (const unsigned int*)&c00;
  const unsigned int* u01 = (const unsigned int*)&c01;
  const unsigned int* u10 = (const unsigned int*)&c10;
  const unsigned int* u11 = (const unsigned int*)&c11;
  uint4 outv;
  unsigned int* op = (unsigned int*)&outv;
#pragma unroll
  for (int q = 0; q < 4; ++q) {
    float lo = wq.x * bflo(u00[q]) + wq.y * bflo(u01[q]) +
               wq.z * bflo(u10[q]) + wq.w * bflo(u11[q]);
    float hi = wq.x * bfhi(u00[q]) + wq.y * bfhi(u01[q]) +
               wq.z * bfhi(u10[q]) + wq.w * bfhi(u11[q]);
    op[q] = (__float_as_uint(hi) & 0xffff0000u) | (__float_as_uint(lo) >> 16);
  }
  int idx = ((px >> 4) * 2 + (oct >> 2)) * 64 + ((oct & 3) << 4) + (px & 15);
  int slot = idx ^ ((idx >> 4) & 7);
  *(uint4*)&colf[slot * 8] = outv;
}

// ---------------------------------------------------------------------------
// Fused: offset-conv prologue + bilinear sample + bf16 MFMA GEMM.
// 8x8 px tile, 256 o, 512 thr (8 waves), grid (64,4) = 256 blocks.
// Conv: waves = (kt-half x n-tile), B-frags read directly from staged octet
// windows at tap-shifted positions; halves reduced via s_colf scratch ->
// s_off (bias+clip applied). Main loop: ONE barrier per chunk, cb order
// {2,3,0,1} reuses conv's last two staged buffers.
// ---------------------------------------------------------------------------
__global__ __launch_bounds__(512) void deform_kernel(
    const float* __restrict__ x, const float* __restrict__ obias,
    const unsigned short* __restrict__ wfrag,
    const unsigned short* __restrict__ wfragA, const float* __restrict__ bias,
    float* __restrict__ out) {
  int tid = threadIdx.x;
  int b = blockIdx.y, tile = blockIdx.x;
  int h0 = (tile >> 3) * 8, w0 = (tile & 7) * 8;
  int lane = tid & 63, wv = tid >> 6;

  __shared__ unsigned short s_x8[2][225 * 72];           // octet layout
  __shared__ __align__(16) unsigned short s_colf[2][4096];
  __shared__ __align__(16) float s_w4[9][64][4];
  __shared__ short s_coff[9][64];
  __shared__ float s_off[18 * 64];

  const float* xb = x + (size_t)b * 256 * 4096;

  // ---- conv prologue ----
  int ckt = wv >> 2;  // k-half (kt)
  int cnt = wv & 3;   // n-tile
  int pxcol = lane & 15, kq = lane >> 4;
  int cpx = cnt * 16 + pxcol;
  int cbasepos = ((cpx >> 3) + 2) * 15 + (cpx & 7) + 2;  // ty=tx=0 position
  floatx4 cacc[2];
  cacc[0] = (floatx4)(0.f);
  cacc[1] = (floatx4)(0.f);
  const short8* wA = (const short8*)wfragA;

  stage_cb8(s_x8[0], xb, 0, h0, w0, tid);
  __syncthreads();
  for (int cc = 0; cc < 4; ++cc) {
    if (cc + 1 < 4) stage_cb8(s_x8[(cc + 1) & 1], xb, cc + 1, h0, w0, tid);
    const unsigned short* sx = s_x8[cc & 1];
#pragma unroll
    for (int t = 0; t < 9; ++t) {
      int ci = cc * 9 + t;
      int ty = t / 3, tx = t - ty * 3;
      short8 bfr = *(const short8*)(sx + (cbasepos + ty * 15 + tx) * 72 +
                                    (ckt * 4 + kq) * 8);
      short8 a0 = wA[((ci * 2 + ckt) * 2 + 0) * 64 + lane];
      short8 a1 = wA[((ci * 2 + ckt) * 2 + 1) * 64 + lane];
      cacc[0] =
          __builtin_amdgcn_mfma_f32_16x16x32_bf16(a0, bfr, cacc[0], 0, 0, 0);
      cacc[1] =
          __builtin_amdgcn_mfma_f32_16x16x32_bf16(a1, bfr, cacc[1], 0, 0, 0);
    }
    __syncthreads();
  }
  // reduce the two k-halves via s_colf[0] scratch (8KB), then bias+clip.
  float* scr = (float*)&s_colf[0][0];
  if (ckt == 1) {
    *(floatx4*)&scr[((cnt * 2 + 0) * 64 + lane) * 4] = cacc[0];
    *(floatx4*)&scr[((cnt * 2 + 1) * 64 + lane) * 4] = cacc[1];
  }
  __syncthreads();
  if (ckt == 0) {
    int quad = lane >> 4, col = lane & 15;
#pragma unroll
    for (int mt = 0; mt < 2; ++mt) {
      floatx4 other = *(const floatx4*)&scr[((cnt * 2 + mt) * 64 + lane) * 4];
#pragma unroll
      for (int r = 0; r < 4; ++r) {
        int o = mt * 16 + quad * 4 + r;
        if (o < 18) {
          float v = cacc[mt][r] + other[r] + obias[o];
          v = fminf(fmaxf(v, -1.f), 1.f);
          s_off[o * 64 + cnt * 16 + col] = v;
        }
      }
    }
  }
  __syncthreads();

  // ---- phase 0: bilinear tables from s_off (R6-verified formula) ----
  for (int e = tid; e < 576; e += 512) {
    int n = e >> 6, pe = e & 63;
    int hy = h0 + (pe >> 3), wx = w0 + (pe & 7);
    float dy = s_off[(2 * n) * 64 + pe];
    float dx = s_off[(2 * n + 1) * 64 + pe];
    float fy = dy + (float)(hy - 2 + (n / 3) * 2);
    float fx = dx + (float)(wx - 2 + (n % 3) * 2);
    float y0f = floorf(fy), x0f = floorf(fx);
    float wy1 = fy - y0f, wx1 = fx - x0f;
    float wy0 = 1.f - wy1, wx0 = 1.f - wx1;
    s_coff[n][pe] =
        (short)(((int)y0f - (h0 - 3)) * 15 + ((int)x0f - (w0 - 3)));
    s_w4[n][pe][0] = wy0 * wx0;
    s_w4[n][pe][1] = wy0 * wx1;
    s_w4[n][pe][2] = wy1 * wx0;
    s_w4[n][pe][3] = wy1 * wx1;
  }
  __syncthreads();

  int spx = tid >> 3, soct = tid & 7;
  // prologue: sample exec-chunk 0 = (cb=2, n=0) from buf[0]
  sample_chunk8(s_x8[0], 0, s_colf[0], spx, soct, s_w4, s_coff);
  __syncthreads();

  floatx4 acc[4][2];
#pragma unroll
  for (int i = 0; i < 4; ++i)
#pragma unroll
    for (int j = 0; j < 2; ++j) acc[i][j] = (floatx4)(0.f);

  int oq = wv >> 1, nh = wv & 1;

  for (int si = 0; si < 4; ++si) {
    int cb = (si + 2) & 3;  // exec order {2,3,0,1}
    for (int n = 0; n < 9; ++n) {
      int e = si * 9 + n;
      int cif = cb * 9 + n;
      // A-frags (global/L2; consumed at MFMA below)
      short8 areg[2][4];
      const short8* wg = (const short8*)wfrag + (size_t)cif * 2048;
#pragma unroll
      for (int k2 = 0; k2 < 2; ++k2)
#pragma unroll
        for (int mi = 0; mi < 4; ++mi)
          areg[k2][mi] = wg[((oq * 4 + mi) * 2 + k2) * 64 + lane];

      // stage next cb (direct-LDS, other buffer; cb3 pre-staged by conv)
      if (n == 6 && si >= 1 && si < 3) {
        int ncb = (si + 3) & 3;
        stage_cb8(s_x8[ncb & 1], xb, ncb, h0, w0, tid);
      }

      // sample exec-chunk e+1 -> colf[(e+1)&1]
      if (e + 1 < 36) {
        int nn = n + 1, scb = cb;
        if (nn == 9) {
          nn = 0;
          scb = (si + 3) & 3;
        }
        sample_chunk8(s_x8[scb & 1], nn, s_colf[(e + 1) & 1], spx, soct, s_w4,
                      s_coff);
      }

      // MFMA exec-chunk e from colf[e&1] (slot-swizzled reads)
      const unsigned short* cf = s_colf[e & 1];
#pragma unroll
      for (int k2 = 0; k2 < 2; ++k2) {
        short8 bfr[2];
#pragma unroll
        for (int tn = 0; tn < 2; ++tn) {
          int idx = ((nh * 2 + tn) * 2 + k2) * 64 + lane;
          int slot = idx ^ ((idx >> 4) & 7);
          bfr[tn] = *(const short8*)&cf[slot * 8];
        }
#pragma unroll
        for (int mi = 0; mi < 4; ++mi)
#pragma unroll
          for (int tn = 0; tn < 2; ++tn)
            acc[mi][tn] = __builtin_amdgcn_mfma_f32_16x16x32_bf16(
                areg[k2][mi], bfr[tn], acc[mi][tn], 0, 0, 0);
      }
      __syncthreads();
    }
  }

  // epilogue (R5-verified): C/D col=lane&15, row=quad*4+r
  int quad = lane >> 4, col = lane & 15;
#pragma unroll
  for (int mi = 0; mi < 4; ++mi)
#pragma unroll
    for (int tn = 0; tn < 2; ++tn) {
      int pxo = (nh * 2 + tn) * 16 + col;
      int h = h0 + (pxo >> 3), w = w0 + (pxo & 7);
#pragma unroll
      for (int r = 0; r < 4; ++r) {
        int o = oq * 64 + mi * 16 + quad * 4 + r;
        out[(((size_t)b * 256 + o) * 64 + h) * 64 + w] =
            acc[mi][tn][r] + bias[o];
      }
    }
}

extern "C" void kernel_launch(void* const* d_in, const int* in_sizes, int n_in,
                              void* d_out, int out_size, void* d_ws,
                              size_t ws_size, hipStream_t stream) {
  (void)in_sizes; (void)n_in; (void)out_size; (void)ws_size;
  const float* x        = (const float*)d_in[0];  // (4,256,64,64)
  const float* offset_w = (const float*)d_in[1];  // (18,256,3,3)
  const float* offset_b = (const float*)d_in[2];  // (18,)
  const float* deform_w = (const float*)d_in[3];  // (256,256,3,3)
  const float* deform_b = (const float*)d_in[4];  // (256,)
  float* out = (float*)d_out;

  unsigned short* wfrag = (unsigned short*)d_ws;  // 589824 bf16
  unsigned short* wfragA = wfrag + 589824;        // 73728 bf16

  prep_kernel<<<324, 256, 0, stream>>>(deform_w, offset_w, wfrag, wfragA);
  deform_kernel<<<dim3(64, 4), 512, 0, stream>>>(x, offset_b, wfrag, wfragA,
                                                 deform_b, out);
  hipMemcpyAsync(out + 4194304, deform_w, 589824 * sizeof(float),
                 hipMemcpyDeviceToDevice, stream);
}

// Round 10
// 165.467 us; speedup vs baseline: 1.0560x; 1.0560x over previous
//
#include <hip/hip_runtime.h>

// B=4, C=256, H=W=64, O=256, K=3, PAD=2, DIL=2; offset conv: 18ch 3x3 p1 d1.
// R10 = R8 skeleton (separate conv kernel, reg-prefetch/commit staging, one
// barrier/chunk) + R9's octet LDS layout (corner read = 1 ds_read_b128 for
// 8 ch; colf XOR-slot swizzle) + offset conv re-parallelized (c-split by 8,
// 2048 blocks, stage-once 10x10x32ch octet window).
// K order k = cb*576 + n*64 + cl; all frag layouts R7/R8/R9-verified.

typedef __attribute__((ext_vector_type(8))) short short8;
typedef __attribute__((ext_vector_type(4))) float floatx4;

__device__ inline unsigned short f2bf(float f) {  // RNE fp32 -> bf16 bits
  unsigned int u = __float_as_uint(f);
  u += 0x7fff + ((u >> 16) & 1);
  return (unsigned short)(u >> 16);
}
__device__ inline float bflo(unsigned int u) { return __uint_as_float(u << 16); }
__device__ inline float bfhi(unsigned int u) {
  return __uint_as_float(u & 0xffff0000u);
}

// ---------------------------------------------------------------------------
// prep (unchanged, R7/R8-verified).
// wfrag:  [ci=36][mt=16][kt=2][lane=64][j=8], val = dw[o=mt*16+(lane&15)]
//         [c*9+n], c = cb*64+kt*32+(lane>>4)*8+j, cb=ci/9, n=ci%9.
// wfragA: [ci=36][kt=2][mt=2][lane=64][j=8], val = (o<18)?ow[o][c*9+t]:0.
// ---------------------------------------------------------------------------
__global__ __launch_bounds__(256) void prep_kernel(
    const float* __restrict__ dw, const float* __restrict__ ow,
    unsigned short* __restrict__ wfrag, unsigned short* __restrict__ wfragA) {
  int idx = blockIdx.x * 256 + threadIdx.x;
  if (idx < 73728) {
    int ci = idx >> 11;
    int mt = (idx >> 7) & 15;
    int kt = (idx >> 6) & 1;
    int lane = idx & 63;
    int cb = ci / 9, n = ci - cb * 9;
    int o = mt * 16 + (lane & 15);
    int cbase = cb * 64 + kt * 32 + (lane >> 4) * 8;
    short8 v;
#pragma unroll
    for (int j = 0; j < 8; ++j)
      v[j] = (short)f2bf(dw[o * 2304 + (cbase + j) * 9 + n]);
    *((short8*)wfrag + idx) = v;
  } else {
    int e = idx - 73728;
    if (e < 9216) {
      int ci = e >> 8;
      int kt = (e >> 7) & 1;
      int mt = (e >> 6) & 1;
      int lane = e & 63;
      int cb = ci / 9, t = ci - cb * 9;
      int o = mt * 16 + (lane & 15);
      int cbase = cb * 64 + kt * 32 + (lane >> 4) * 8;
      short8 v;
      if (o < 18) {
#pragma unroll
        for (int j = 0; j < 8; ++j)
          v[j] = (short)f2bf(ow[o * 2304 + (cbase + j) * 9 + t]);
      } else {
        v = (short8)0;
      }
      *((short8*)wfragA + e) = v;
    }
  }
}

// ---------------------------------------------------------------------------
// Offset conv via MFMA, c-split by 8: grid (64,4,8) = 2048 blocks (8/CU),
// 32 ch per block (= one kt-half of one cb). Stage ONCE: 10x10 window
// (origin h0-1, w0-1) in octet layout [pos=ry*10+rx][32 ch], OOB=0.
// 9 t-steps: B-frag = one ds_read_b128 (8 ch, kq-selected), 2 MFMA (mt).
// atomicAdd fp32 partials to off_buf (zeroed per launch).
// ---------------------------------------------------------------------------
__global__ __launch_bounds__(256) void offset_conv_mfma(
    const float* __restrict__ x, const unsigned short* __restrict__ wfragA,
    float* __restrict__ off_buf) {
  int tid = threadIdx.x;
  int b = blockIdx.y, tile = blockIdx.x, cg = blockIdx.z;
  int h0 = (tile >> 3) * 8, w0 = (tile & 7) * 8;
  int lane = tid & 63, wv = tid >> 6;

  __shared__ unsigned short s_c8[100 * 32];  // [pos][32 ch]

  const float* xb = x + (size_t)b * 256 * 4096;

  // stage: 400 units = pos(100) x oct(4); pos fastest for coalescing
  for (int e = tid; e < 400; e += 256) {
    int oct = e / 100, pos = e - oct * 100;
    int ry = pos / 10, rx = pos - ry * 10;
    int gy = h0 - 1 + ry, gx = w0 - 1 + rx;
    bool ok = (gy >= 0 && gy < 64 && gx >= 0 && gx < 64);
    const float* p0 =
        xb + ((size_t)(cg * 32 + oct * 8)) * 4096 + (ok ? gy * 64 + gx : 0);
    unsigned int s[8];
#pragma unroll
    for (int j = 0; j < 8; ++j)
      s[j] = ok ? (unsigned int)f2bf(p0[(size_t)j * 4096]) : 0u;
    uint4 v;
    v.x = s[0] | (s[1] << 16);
    v.y = s[2] | (s[3] << 16);
    v.z = s[4] | (s[5] << 16);
    v.w = s[6] | (s[7] << 16);
    *(uint4*)&s_c8[pos * 32 + oct * 8] = v;
  }
  __syncthreads();

  floatx4 acc[2];
  acc[0] = (floatx4)(0.f);
  acc[1] = (floatx4)(0.f);

  int px = wv * 16 + (lane & 15);  // wave = n-tile of 16 px
  int pxy = px >> 3, pxx = px & 7;
  int kq = lane >> 4;
  int cb = cg >> 1, ckt = cg & 1;
  const short8* wA = (const short8*)wfragA;

#pragma unroll
  for (int t = 0; t < 9; ++t) {
    int ci = cb * 9 + t;
    int ty = t / 3, tx = t - ty * 3;
    int pos = (pxy + ty) * 10 + (pxx + tx);
    short8 bfr = *(const short8*)&s_c8[pos * 32 + kq * 8];
    short8 a0 = wA[((ci * 2 + ckt) * 2 + 0) * 64 + lane];
    short8 a1 = wA[((ci * 2 + ckt) * 2 + 1) * 64 + lane];
    acc[0] = __builtin_amdgcn_mfma_f32_16x16x32_bf16(a0, bfr, acc[0], 0, 0, 0);
    acc[1] = __builtin_amdgcn_mfma_f32_16x16x32_bf16(a1, bfr, acc[1], 0, 0, 0);
  }

  // epilogue (R6/R8-verified): atomic partial sums, o<18
  int quad = lane >> 4, col = lane & 15;
  int pp2 = wv * 16 + col;
  int hh = h0 + (pp2 >> 3), ww = w0 + (pp2 & 7);
#pragma unroll
  for (int mt = 0; mt < 2; ++mt)
#pragma unroll
    for (int r = 0; r < 4; ++r) {
      int o = mt * 16 + quad * 4 + r;
      if (o < 18)
        atomicAdd(&off_buf[(((size_t)b * 18 + o) * 64 + hh) * 64 + ww],
                  acc[mt][r]);
    }
}

// ---------------------------------------------------------------------------
// Sampler (R9-verified): thread = (px = tid>>3, oct = tid&7). 4 corner
// ds_read_b128 (8 ch) -> bilinear -> truncate-bf16 -> one ds_write_b128 at
// XOR-swizzled colf slot. kl == cl = oct*8+j.
// ---------------------------------------------------------------------------
__device__ __forceinline__ void sample_chunk8(
    const unsigned short* __restrict__ sx, int n,
    unsigned short* __restrict__ colf, int px, int oct,
    const float (*sw4)[64][4], const short (*scoff)[64]) {
  float4 wq = *(const float4*)&sw4[n][px][0];
  const unsigned short* p = sx + (int)scoff[n][px] * 72 + oct * 8;
  uint4 c00 = *(const uint4*)(p);
  uint4 c01 = *(const uint4*)(p + 72);
  uint4 c10 = *(const uint4*)(p + 15 * 72);
  uint4 c11 = *(const uint4*)(p + 16 * 72);
  const unsigned int* u00 = (const unsigned int*)&c00;
  const unsigned int* u01 = (const unsigned int*)&c01;
  const unsigned int* u10 = (const unsigned int*)&c10;
  const unsigned int* u11 = (const unsigned int*)&c11;
  uint4 outv;
  unsigned int* op = (unsigned int*)&outv;
#pragma unroll
  for (int q = 0; q < 4; ++q) {
    float lo = wq.x * bflo(u00[q]) + wq.y * bflo(u01[q]) +
               wq.z * bflo(u10[q]) + wq.w * bflo(u11[q]);
    float hi = wq.x * bfhi(u00[q]) + wq.y * bfhi(u01[q]) +
               wq.z * bfhi(u10[q]) + wq.w * bfhi(u11[q]);
    op[q] = (__float_as_uint(hi) & 0xffff0000u) | (__float_as_uint(lo) >> 16);
  }
  int idx = ((px >> 4) * 2 + (oct >> 2)) * 64 + ((oct & 3) << 4) + (px & 15);
  int slot = idx ^ ((idx >> 4) & 7);
  *(uint4*)&colf[slot * 8] = outv;
}

// ---------------------------------------------------------------------------
// Fused bilinear sample + bf16 MFMA GEMM. 8x8 px tile, 256 o, 512 thr,
// grid (64,4). x in octet layout [pos=ry*15+rx][64ch] (stride 72 shorts),
// double-buffered per cb; staging = reg-prefetch at n==6, commit n==7
// (R8 pattern). colf dbuf + XOR swizzle. ONE barrier per chunk.
// ---------------------------------------------------------------------------
__global__ __launch_bounds__(512) void deform_kernel(
    const float* __restrict__ x, const float* __restrict__ off_buf,
    const float* __restrict__ obias, const unsigned short* __restrict__ wfrag,
    const float* __restrict__ bias, float* __restrict__ out) {
  int tid = threadIdx.x;
  int b = blockIdx.y, tile = blockIdx.x;
  int h0 = (tile >> 3) * 8, w0 = (tile & 7) * 8;
  int lane = tid & 63, wv = tid >> 6;
  int oq = wv >> 1, nh = wv & 1;

  __shared__ unsigned short s_x8[2][225 * 72];
  __shared__ __align__(16) unsigned short s_colf[2][4096];
  __shared__ __align__(16) float s_w4[9][64][4];
  __shared__ short s_coff[9][64];

  // phase 0 (R6/R8-verified): bias + clip fused; off_buf holds raw sums.
  for (int e = tid; e < 576; e += 512) {
    int n = e >> 6, pe = e & 63;
    int hy = h0 + (pe >> 3), wx = w0 + (pe & 7);
    float dy =
        off_buf[(((size_t)b * 18 + 2 * n) * 64 + hy) * 64 + wx] + obias[2 * n];
    float dx = off_buf[(((size_t)b * 18 + 2 * n + 1) * 64 + hy) * 64 + wx] +
               obias[2 * n + 1];
    dy = fminf(fmaxf(dy, -1.f), 1.f);
    dx = fminf(fmaxf(dx, -1.f), 1.f);
    float fy = dy + (float)(hy - 2 + (n / 3) * 2);
    float fx = dx + (float)(wx - 2 + (n % 3) * 2);
    float y0f = floorf(fy), x0f = floorf(fx);
    float wy1 = fy - y0f, wx1 = fx - x0f;
    float wy0 = 1.f - wy1, wx0 = 1.f - wx1;
    s_coff[n][pe] =
        (short)(((int)y0f - (h0 - 3)) * 15 + ((int)x0f - (w0 - 3)));
    s_w4[n][pe][0] = wy0 * wx0;
    s_w4[n][pe][1] = wy0 * wx1;
    s_w4[n][pe][2] = wy1 * wx0;
    s_w4[n][pe][3] = wy1 * wx1;
  }

  const float* xb = x + (size_t)b * 256 * 4096;
  // stage cb0 -> buf0 (direct; pos fastest for coalescing)
  for (int e = tid; e < 1800; e += 512) {
    int oct = e / 225, pos = e - oct * 225;
    int ry = pos / 15, rx = pos - ry * 15;
    int gy = h0 - 3 + ry, gx = w0 - 3 + rx;
    bool ok = (gy >= 0 && gy < 64 && gx >= 0 && gx < 64);
    const float* p0 = xb + ((size_t)(oct * 8)) * 4096 + (ok ? gy * 64 + gx : 0);
    unsigned int s[8];
#pragma unroll
    for (int j = 0; j < 8; ++j)
      s[j] = ok ? (unsigned int)f2bf(p0[(size_t)j * 4096]) : 0u;
    uint4 v;
    v.x = s[0] | (s[1] << 16);
    v.y = s[2] | (s[3] << 16);
    v.z = s[4] | (s[5] << 16);
    v.w = s[6] | (s[7] << 16);
    *(uint4*)&s_x8[0][pos * 72 + oct * 8] = v;
  }
  __syncthreads();

  int spx = tid >> 3, soct = tid & 7;
  // prologue: sample chunk 0 (cb0, n0) -> colf[0]
  sample_chunk8(s_x8[0], 0, s_colf[0], spx, soct, s_w4, s_coff);
  __syncthreads();

  floatx4 acc[4][2];
#pragma unroll
  for (int i = 0; i < 4; ++i)
#pragma unroll
    for (int j = 0; j < 2; ++j) acc[i][j] = (floatx4)(0.f);

  uint4 pr[4];

  for (int cb = 0; cb < 4; ++cb) {
    for (int n = 0; n < 9; ++n) {
      int ci = cb * 9 + n;
      // A-frags (global/L2; consumed at MFMA below)
      short8 areg[2][4];
      const short8* wg = (const short8*)wfrag + (size_t)ci * 2048;
#pragma unroll
      for (int k2 = 0; k2 < 2; ++k2)
#pragma unroll
        for (int mi = 0; mi < 4; ++mi)
          areg[k2][mi] = wg[((oq * 4 + mi) * 2 + k2) * 64 + lane];

      // staging prefetch (regs) for cb+1 at n==6; commit at n==7 (R8 pattern)
      if (n == 6 && cb < 3) {
#pragma unroll
        for (int u = 0; u < 4; ++u) {
          int e = tid + u * 512;
          pr[u] = make_uint4(0u, 0u, 0u, 0u);
          if (e < 1800) {
            int oct = e / 225, pos = e - oct * 225;
            int ry = pos / 15, rx = pos - ry * 15;
            int gy = h0 - 3 + ry, gx = w0 - 3 + rx;
            bool ok = (gy >= 0 && gy < 64 && gx >= 0 && gx < 64);
            if (ok) {
              const float* p0 =
                  xb + ((size_t)((cb + 1) * 64 + oct * 8)) * 4096 +
                  gy * 64 + gx;
              unsigned int s[8];
#pragma unroll
              for (int j = 0; j < 8; ++j)
                s[j] = (unsigned int)f2bf(p0[(size_t)j * 4096]);
              pr[u].x = s[0] | (s[1] << 16);
              pr[u].y = s[2] | (s[3] << 16);
              pr[u].z = s[4] | (s[5] << 16);
              pr[u].w = s[6] | (s[7] << 16);
            }
          }
        }
      }
      if (n == 7 && cb < 3) {
#pragma unroll
        for (int u = 0; u < 4; ++u) {
          int e = tid + u * 512;
          if (e < 1800) {
            int oct = e / 225, pos = e - oct * 225;
            *(uint4*)&s_x8[(cb + 1) & 1][pos * 72 + oct * 8] = pr[u];
          }
        }
      }

      // sample chunk ci+1 -> colf[(ci+1)&1]
      if (ci + 1 < 36) {
        int nn = n + 1, cbn = cb;
        if (nn == 9) {
          nn = 0;
          cbn = cb + 1;
        }
        sample_chunk8(s_x8[cbn & 1], nn, s_colf[(ci + 1) & 1], spx, soct,
                      s_w4, s_coff);
      }

      // MFMA chunk ci from colf[ci&1] (slot-swizzled reads, R9-verified)
      const unsigned short* cf = s_colf[ci & 1];
#pragma unroll
      for (int k2 = 0; k2 < 2; ++k2) {
        short8 bfr[2];
#pragma unroll
        for (int tn = 0; tn < 2; ++tn) {
          int idx = ((nh * 2 + tn) * 2 + k2) * 64 + lane;
          int slot = idx ^ ((idx >> 4) & 7);
          bfr[tn] = *(const short8*)&cf[slot * 8];
        }
#pragma unroll
        for (int mi = 0; mi < 4; ++mi)
#pragma unroll
          for (int tn = 0; tn < 2; ++tn)
            acc[mi][tn] = __builtin_amdgcn_mfma_f32_16x16x32_bf16(
                areg[k2][mi], bfr[tn], acc[mi][tn], 0, 0, 0);
      }
      __syncthreads();
    }
  }

  // epilogue (R5-verified): C/D col=lane&15, row=quad*4+r
  int quad = lane >> 4, col = lane & 15;
#pragma unroll
  for (int mi = 0; mi < 4; ++mi)
#pragma unroll
    for (int tn = 0; tn < 2; ++tn) {
      int pxo = (nh * 2 + tn) * 16 + col;
      int h = h0 + (pxo >> 3), w = w0 + (pxo & 7);
#pragma unroll
      for (int r = 0; r < 4; ++r) {
        int o = oq * 64 + mi * 16 + quad * 4 + r;
        out[(((size_t)b * 256 + o) * 64 + h) * 64 + w] =
            acc[mi][tn][r] + bias[o];
      }
    }
}

extern "C" void kernel_launch(void* const* d_in, const int* in_sizes, int n_in,
                              void* d_out, int out_size, void* d_ws,
                              size_t ws_size, hipStream_t stream) {
  (void)in_sizes; (void)n_in; (void)out_size; (void)ws_size;
  const float* x        = (const float*)d_in[0];  // (4,256,64,64)
  const float* offset_w = (const float*)d_in[1];  // (18,256,3,3)
  const float* offset_b = (const float*)d_in[2];  // (18,)
  const float* deform_w = (const float*)d_in[3];  // (256,256,3,3)
  const float* deform_b = (const float*)d_in[4];  // (256,)
  float* out = (float*)d_out;

  float* off_buf = (float*)d_ws;                                // 294912 f
  unsigned short* wfrag = (unsigned short*)(off_buf + 294912);  // 589824 bf16
  unsigned short* wfragA = wfrag + 589824;                      // 73728 bf16

  hipMemsetAsync(off_buf, 0, 294912 * sizeof(float), stream);
  prep_kernel<<<324, 256, 0, stream>>>(deform_w, offset_w, wfrag, wfragA);
  offset_conv_mfma<<<dim3(64, 4, 8), 256, 0, stream>>>(x, wfragA, off_buf);
  deform_kernel<<<dim3(64, 4), 512, 0, stream>>>(x, off_buf, offset_b, wfrag,
                                                 deform_b, out);
  hipMemcpyAsync(out + 4194304, deform_w, 589824 * sizeof(float),
                 hipMemcpyDeviceToDevice, stream);
}